// Round 4
// baseline (219.087 us; speedup 1.0000x reference)
//
#include <hip/hip_runtime.h>

typedef unsigned int   u32;
typedef unsigned short u16;
typedef __attribute__((ext_vector_type(8))) short short8;
typedef __attribute__((ext_vector_type(4))) float f32x4;

// B=64 T=256 C=512 H=8 D=64; M = B*T = 16384; K = 512; Nqkv = 1536

__device__ __forceinline__ u16 f2bf(float f) {
    u32 u = __float_as_uint(f);
    u += 0x7fffu + ((u >> 16) & 1u);   // RNE
    return (u16)(u >> 16);
}

// async global->LDS 16B (direct DMA, no VGPR round-trip). LDS dest is
// wave-uniform base + lane*16; callers must pass lptr == that address.
__device__ __forceinline__ void gload_lds16(const u16* g, u16* l) {
    __builtin_amdgcn_global_load_lds(
        (const __attribute__((address_space(1))) u32*)(const void*)g,
        (__attribute__((address_space(3))) u32*)(void*)l, 16, 0, 0);
}

// ---------------- cast x (fp32 -> bf16) ----------------
__global__ void cast_x_kernel(const float* __restrict__ x, u16* __restrict__ xb) {
    int i = blockIdx.x * 256 + threadIdx.x;
    float4 v = ((const float4*)x)[i];
    ushort4 o;
    o.x = f2bf(v.x); o.y = f2bf(v.y); o.z = f2bf(v.z); o.w = f2bf(v.w);
    ((ushort4*)xb)[i] = o;
}

// -------- pack wq|wk|wv -> bf16 [1536][512] transposed --------
__global__ void pack_wqkv_kernel(const float* __restrict__ wq, const float* __restrict__ wk,
                                 const float* __restrict__ wv, u16* __restrict__ wt) {
    int i = blockIdx.x * 256 + threadIdx.x;
    int n = i >> 9, c = i & 511;
    int proj = n >> 9, hd = n & 511;
    int h = hd >> 6, d = hd & 63;
    const float* w = (proj == 0) ? wq : (proj == 1) ? wk : wv;
    wt[(size_t)n * 512 + c] = f2bf(w[h * 32768 + c * 64 + d]);
}

// -------- pack wo [512][512] -> bf16 transposed [n][k] --------
__global__ void pack_wo_kernel(const float* __restrict__ wo, u16* __restrict__ wt) {
    int i = blockIdx.x * 256 + threadIdx.x;
    int n = i >> 9, k = i & 511;
    wt[(size_t)n * 512 + k] = f2bf(wo[(size_t)k * 512 + n]);
}

// ---------------- 128x128 bf16 MFMA GEMM, K=512, TN, global_load_lds staging ----
// LDS tiles: unpadded row-major 128x32 (64B row stride). Staging: each thread
// DMAs one 16B chunk per call; lane-contiguous LDS dest (lrow=tid>>2,seg=tid&3
// -> base + lane*16). Fragment b128 reads spread 8 lanes/4-bank-group uniform.
// EPI=0: QKV epilogue (V scatters transposed to Vt[head][d][t]).
// EPI=1: out epilogue (fp32 + bo).
template<int EPI>
__global__ __launch_bounds__(256)
void gemm128_kernel(const u16* __restrict__ A, const u16* __restrict__ Bt,
                    float* __restrict__ outf, const float* __restrict__ bo,
                    u16* __restrict__ Qb, u16* __restrict__ Kb, u16* __restrict__ Vb,
                    const float* __restrict__ bq, const float* __restrict__ bk,
                    const float* __restrict__ bv) {
    __shared__ __align__(16) u16 As[128 * 32];
    __shared__ __align__(16) u16 Bs[128 * 32];
    const int tid = threadIdx.x;
    const int m0 = blockIdx.y * 128;
    const int n0 = blockIdx.x * 128;
    const int lrow = tid >> 2;            // 0..63
    const int seg  = tid & 3;
    const u16* Ag = A  + (size_t)(m0 + lrow) * 512 + seg * 8;
    const u16* Bg = Bt + (size_t)(n0 + lrow) * 512 + seg * 8;
    u16* Asl = As + lrow * 32 + seg * 8;
    u16* Bsl = Bs + lrow * 32 + seg * 8;

    const int w = tid >> 6, lane = tid & 63;
    const int wrow = (w >> 1) * 64, wcol = (w & 1) * 64;
    const int lm = lane & 15, quad = lane >> 4;

    f32x4 acc[4][4] = {};

    for (int kt = 0; kt < 16; ++kt) {
        __syncthreads();                  // prior LDS reads done before DMA overwrite
        gload_lds16(Ag + kt * 32,             Asl);
        gload_lds16(Ag + 64 * 512 + kt * 32,  Asl + 64 * 32);
        gload_lds16(Bg + kt * 32,             Bsl);
        gload_lds16(Bg + 64 * 512 + kt * 32,  Bsl + 64 * 32);
        __syncthreads();                  // drains vmcnt: DMA complete
        short8 af[4], bf[4];
        #pragma unroll
        for (int mi = 0; mi < 4; ++mi)
            af[mi] = *(const short8*)(As + (wrow + mi * 16 + lm) * 32 + quad * 8);
        #pragma unroll
        for (int ni = 0; ni < 4; ++ni)
            bf[ni] = *(const short8*)(Bs + (wcol + ni * 16 + lm) * 32 + quad * 8);
        #pragma unroll
        for (int mi = 0; mi < 4; ++mi)
            #pragma unroll
            for (int ni = 0; ni < 4; ++ni)
                acc[mi][ni] = __builtin_amdgcn_mfma_f32_16x16x32_bf16(af[mi], bf[ni], acc[mi][ni], 0, 0, 0);
    }

    if (EPI == 1) {
        #pragma unroll
        for (int ni = 0; ni < 4; ++ni) {
            int ncol = n0 + wcol + ni * 16 + lm;
            float bias = bo[ncol];
            #pragma unroll
            for (int mi = 0; mi < 4; ++mi) {
                int mbase = m0 + wrow + mi * 16 + quad * 4;
                #pragma unroll
                for (int r = 0; r < 4; ++r)
                    outf[(size_t)(mbase + r) * 512 + ncol] = acc[mi][ni][r] + bias;
            }
        }
    } else {
        #pragma unroll
        for (int ni = 0; ni < 4; ++ni) {
            int ncol = n0 + wcol + ni * 16 + lm;
            int proj = ncol >> 9, hd = ncol & 511;
            int h = hd >> 6, d = hd & 63;
            const float* bptr = (proj == 0) ? bq : (proj == 1) ? bk : bv;
            u16* dst = (proj == 0) ? Qb : (proj == 1) ? Kb : Vb;
            float bias = bptr[hd];
            #pragma unroll
            for (int mi = 0; mi < 4; ++mi) {
                int mbase = m0 + wrow + mi * 16 + quad * 4;
                #pragma unroll
                for (int r = 0; r < 4; ++r) {
                    int mrow = mbase + r;
                    int b = mrow >> 8, t = mrow & 255;
                    size_t idx = (proj == 2)
                        ? ((size_t)((b * 8 + h) * 64 + d) * 256 + t)     // Vt [head][d][t]
                        : ((size_t)((b * 8 + h) * 256 + t) * 64 + d);   // Q/K [head][t][d]
                    dst[idx] = f2bf(acc[mi][ni][r] + bias);
                }
            }
        }
    }
}

// ---------------- MFMA flash attention ----------------
// TWO wgs per (b,h) for occupancy (4 wg/CU): iset=0 owns i in {0,3} (1+4=5
// j-tiles), iset=1 owns i in {1,2} (2+3=5) — balanced. K [256][64] and
// Vt [64][256] staged in LDS (16B-chunk XOR swizzle). Wave w owns 16 Q-rows
// at t0 = i*64 + w*16. P round-trips C/D->LDS->A-layout through a per-wave
// 2KB buffer; write->read and read->next-write bracketed by __syncthreads()
// (all waves run identical trip counts).
__global__ __launch_bounds__(256)
void attn_mfma_kernel(const u16* __restrict__ Qg, const u16* __restrict__ Kg,
                      const u16* __restrict__ Vtg, u16* __restrict__ attn) {
    __shared__ __align__(16) u16 lds[36864];   // K:0..16383 | Vt:16384..32767 | P: 32768 + w*1024
    const int head = blockIdx.x >> 1;
    const int iset = blockIdx.x & 1;
    const int b = head >> 3, h = head & 7;
    const int tid = threadIdx.x;
    const size_t hb = (size_t)head * 16384;

    {
        const uint4* Ksrc = (const uint4*)(Kg + hb);
        const uint4* Vsrc = (const uint4*)(Vtg + hb);
        uint4* L4 = (uint4*)lds;
        #pragma unroll
        for (int it = 0; it < 8; ++it) {
            int g = it * 256 + tid;
            int kr = g >> 3, kc = g & 7;
            L4[kr * 8 + (kc ^ (kr & 7))] = Ksrc[g];
            int vr = g >> 5, vc = g & 31;
            L4[2048 + vr * 32 + (vc ^ (vr & 7))] = Vsrc[g];
        }
    }
    __syncthreads();

    const int w = tid >> 6, lane = tid & 63;
    const int lm = lane & 15, quad = lane >> 4;
    const int l7 = lm & 7;

    const int kx0 = (quad ^ l7) * 8;          // k-chunk f=0
    const int kx1 = ((4 + quad) ^ l7) * 8;    // k-chunk f=1
    const u16* Kbase = lds + lm * 64;                 // + j*4096 + ni*1024 + kx
    const u16* Vbase = lds + 16384 + lm * 256;        // + nd*4096 + j*64 + kx
    const int Pbase = 32768 + w * 1024;
    const int x0 = (lm >> 3) & 1;
    const int pw_even = Pbase + quad * 16 + l7 + x0 * 8;         // rr even
    const int pw_odd  = Pbase + quad * 16 + l7 + (x0 ^ 1) * 8;   // rr odd
    const int pr0 = Pbase + ((lm & 3) * 4 + (quad >> 1)) * 64
                  + (2 * (lm >> 2) + ((quad & 1) ^ (lm & 1))) * 8;

    #pragma unroll 1
    for (int ii = 0; ii < 2; ++ii) {
        const int i = iset ? (ii ? 2 : 1) : (ii ? 3 : 0);
        const int t0 = i * 64 + w * 16;
        short8 qa0 = *(const short8*)(Qg + hb + (size_t)(t0 + lm) * 64 + quad * 8);
        short8 qa1 = *(const short8*)(Qg + hb + (size_t)(t0 + lm) * 64 + 32 + quad * 8);
        f32x4 O[4] = {};
        float mr[4] = {-INFINITY, -INFINITY, -INFINITY, -INFINITY};
        float lr[4] = {0.f, 0.f, 0.f, 0.f};

        #pragma unroll 1
        for (int j = 0; j <= i; ++j) {
            f32x4 S[4] = {};
            #pragma unroll
            for (int ni = 0; ni < 4; ++ni) {
                const u16* kp = Kbase + j * 4096 + ni * 1024;
                short8 kb0 = *(const short8*)(kp + kx0);
                short8 kb1 = *(const short8*)(kp + kx1);
                S[ni] = __builtin_amdgcn_mfma_f32_16x16x32_bf16(qa0, kb0, S[ni], 0, 0, 0);
                S[ni] = __builtin_amdgcn_mfma_f32_16x16x32_bf16(qa1, kb1, S[ni], 0, 0, 0);
            }
            if (j == i) {
                #pragma unroll
                for (int ni = 0; ni < 4; ++ni) {
                    int scol = ni * 16 + lm;
                    #pragma unroll
                    for (int rr = 0; rr < 4; ++rr) {
                        int tloc = w * 16 + quad * 4 + rr;
                        S[ni][rr] = (scol > tloc) ? -INFINITY : S[ni][rr] * 0.125f;
                    }
                }
            } else {
                #pragma unroll
                for (int ni = 0; ni < 4; ++ni)
                    #pragma unroll
                    for (int rr = 0; rr < 4; ++rr)
                        S[ni][rr] *= 0.125f;
            }
            float alpha[4];
            #pragma unroll
            for (int rr = 0; rr < 4; ++rr) {
                float mx = fmaxf(fmaxf(S[0][rr], S[1][rr]), fmaxf(S[2][rr], S[3][rr]));
                mx = fmaxf(mx, __shfl_xor(mx, 1));
                mx = fmaxf(mx, __shfl_xor(mx, 2));
                mx = fmaxf(mx, __shfl_xor(mx, 4));
                mx = fmaxf(mx, __shfl_xor(mx, 8));
                float mnew = fmaxf(mr[rr], mx);
                alpha[rr] = __expf(mr[rr] - mnew);   // 0 on first tile (-inf - finite)
                mr[rr] = mnew;
            }
            __syncthreads();   // previous iter's P reads complete before overwrite
            float rs[4] = {0.f, 0.f, 0.f, 0.f};
            #pragma unroll
            for (int ni = 0; ni < 4; ++ni) {
                #pragma unroll
                for (int rr = 0; rr < 4; ++rr) {
                    float p = __expf(S[ni][rr] - mr[rr]);   // 0 for masked (-inf)
                    rs[rr] += p;
                    int addr = ((rr & 1) ? pw_odd : pw_even) + (rr * 4 + ni) * 64;
                    lds[addr] = f2bf(p);
                }
            }
            #pragma unroll
            for (int rr = 0; rr < 4; ++rr) {
                float s = rs[rr];
                s += __shfl_xor(s, 1);
                s += __shfl_xor(s, 2);
                s += __shfl_xor(s, 4);
                s += __shfl_xor(s, 8);
                lr[rr] = lr[rr] * alpha[rr] + s;
                O[0][rr] *= alpha[rr]; O[1][rr] *= alpha[rr];
                O[2][rr] *= alpha[rr]; O[3][rr] *= alpha[rr];
            }
            __syncthreads();   // P writes visible before A-layout reads
            short8 pa0 = *(const short8*)(lds + pr0);
            short8 pa1 = *(const short8*)(lds + pr0 + 128);
            #pragma unroll
            for (int nd = 0; nd < 4; ++nd) {
                const u16* vp = Vbase + nd * 4096 + j * 64;
                short8 vb0 = *(const short8*)(vp + kx0);
                short8 vb1 = *(const short8*)(vp + kx1);
                O[nd] = __builtin_amdgcn_mfma_f32_16x16x32_bf16(pa0, vb0, O[nd], 0, 0, 0);
                O[nd] = __builtin_amdgcn_mfma_f32_16x16x32_bf16(pa1, vb1, O[nd], 0, 0, 0);
            }
        }
        #pragma unroll
        for (int rr = 0; rr < 4; ++rr) {
            float inv = 1.0f / lr[rr];
            int t = t0 + quad * 4 + rr;
            u16* op = attn + (size_t)(b * 256 + t) * 512 + h * 64 + lm;
            op[0]  = f2bf(O[0][rr] * inv);
            op[16] = f2bf(O[1][rr] * inv);
            op[32] = f2bf(O[2][rr] * inv);
            op[48] = f2bf(O[3][rr] * inv);
        }
    }
}

extern "C" void kernel_launch(void* const* d_in, const int* in_sizes, int n_in,
                              void* d_out, int out_size, void* d_ws, size_t ws_size,
                              hipStream_t stream) {
    const float* x  = (const float*)d_in[0];
    const float* wq = (const float*)d_in[1];
    const float* wk = (const float*)d_in[2];
    const float* wv = (const float*)d_in[3];
    const float* bq = (const float*)d_in[4];
    const float* bk = (const float*)d_in[5];
    const float* bv = (const float*)d_in[6];
    const float* wo = (const float*)d_in[7];
    const float* bo = (const float*)d_in[8];
    float* out = (float*)d_out;

    char* ws = (char*)d_ws;
    const size_t SZ = 16777216;                  // 16384*512*2 bytes
    u16* xb    = (u16*)(ws);
    u16* Qb    = (u16*)(ws + SZ);
    u16* Kb    = (u16*)(ws + 2 * SZ);
    u16* Vt    = (u16*)(ws + 3 * SZ);            // [head][d][t] (written by gemm<0>)
    u16* attn  = (u16*)(ws + 4 * SZ);
    u16* wqkvT = (u16*)(ws + 5 * SZ);
    u16* woT   = (u16*)(ws + 5 * SZ + 1572864);

    cast_x_kernel<<<8192, 256, 0, stream>>>(x, xb);
    pack_wqkv_kernel<<<3072, 256, 0, stream>>>(wq, wk, wv, wqkvT);
    pack_wo_kernel<<<1024, 256, 0, stream>>>(wo, woT);

    gemm128_kernel<0><<<dim3(12, 128), 256, 0, stream>>>(
        xb, wqkvT, nullptr, nullptr, Qb, Kb, Vt, bq, bk, bv);

    attn_mfma_kernel<<<1024, 256, 0, stream>>>(Qb, Kb, Vt, attn);

    gemm128_kernel<1><<<dim3(4, 128), 256, 0, stream>>>(
        attn, woT, out, bo, nullptr, nullptr, nullptr, nullptr, nullptr, nullptr);
}

// Round 5
// 212.642 us; speedup vs baseline: 1.0303x; 1.0303x over previous
//
#include <hip/hip_runtime.h>

typedef unsigned int   u32;
typedef unsigned short u16;
typedef __attribute__((ext_vector_type(8))) short short8;
typedef __attribute__((ext_vector_type(4))) float f32x4;

// B=64 T=256 C=512 H=8 D=64; M = B*T = 16384; K = 512; Nqkv = 1536

__device__ __forceinline__ u16 f2bf(float f) {
    u32 u = __float_as_uint(f);
    u += 0x7fffu + ((u >> 16) & 1u);   // RNE
    return (u16)(u >> 16);
}

// async global->LDS 16B (direct DMA, no VGPR round-trip). LDS dest is
// wave-uniform base + lane*16.
__device__ __forceinline__ void gload_lds16(const u16* g, u16* l) {
    __builtin_amdgcn_global_load_lds(
        (const __attribute__((address_space(1))) u32*)(const void*)g,
        (__attribute__((address_space(3))) u32*)(void*)l, 16, 0, 0);
}

// ---------------- cast x (fp32 -> bf16) ----------------
__global__ void cast_x_kernel(const float* __restrict__ x, u16* __restrict__ xb) {
    int i = blockIdx.x * 256 + threadIdx.x;
    float4 v = ((const float4*)x)[i];
    ushort4 o;
    o.x = f2bf(v.x); o.y = f2bf(v.y); o.z = f2bf(v.z); o.w = f2bf(v.w);
    ((ushort4*)xb)[i] = o;
}

// -------- pack wq|wk|wv -> bf16 [1536][512] transposed --------
__global__ void pack_wqkv_kernel(const float* __restrict__ wq, const float* __restrict__ wk,
                                 const float* __restrict__ wv, u16* __restrict__ wt) {
    int i = blockIdx.x * 256 + threadIdx.x;
    int n = i >> 9, c = i & 511;
    int proj = n >> 9, hd = n & 511;
    int h = hd >> 6, d = hd & 63;
    const float* w = (proj == 0) ? wq : (proj == 1) ? wk : wv;
    wt[(size_t)n * 512 + c] = f2bf(w[h * 32768 + c * 64 + d]);
}

// -------- pack wo [512][512] -> bf16 transposed [n][k] --------
__global__ void pack_wo_kernel(const float* __restrict__ wo, u16* __restrict__ wt) {
    int i = blockIdx.x * 256 + threadIdx.x;
    int n = i >> 9, k = i & 511;
    wt[(size_t)n * 512 + k] = f2bf(wo[(size_t)k * 512 + n]);
}

// ---------------- 128x128 bf16 MFMA GEMM, K=512, TN, global_load_lds staging ----
// 1-D grid, XCD-aware swizzle: hw maps linear block i -> XCD i%8 (round-robin,
// perf heuristic only). XCD x owns m-stripes [x*16, x*16+16) for ALL NT
// n-tiles -> per-XCD L2 working set = 2.1 MB A-chunk + full B (<=1.6 MB),
// so A is fetched once per XCD (not NT times) and B is L2-resident.
// EPI=0: QKV epilogue (V scatters transposed to Vt[head][d][t]).
// EPI=1: out epilogue (fp32 + bo).
template<int EPI, int NT>
__global__ __launch_bounds__(256)
void gemm128_kernel(const u16* __restrict__ A, const u16* __restrict__ Bt,
                    float* __restrict__ outf, const float* __restrict__ bo,
                    u16* __restrict__ Qb, u16* __restrict__ Kb, u16* __restrict__ Vb,
                    const float* __restrict__ bq, const float* __restrict__ bk,
                    const float* __restrict__ bv) {
    __shared__ __align__(16) u16 As[128 * 32];
    __shared__ __align__(16) u16 Bs[128 * 32];
    const int tid = threadIdx.x;
    const int bid = blockIdx.x;
    const int xcd = bid & 7;
    const int k8  = bid >> 3;                 // 0 .. 16*NT-1
    const int m0 = (xcd * 16 + k8 / NT) * 128;
    const int n0 = (k8 % NT) * 128;
    const int lrow = tid >> 2;            // 0..63
    const int seg  = tid & 3;
    const u16* Ag = A  + (size_t)(m0 + lrow) * 512 + seg * 8;
    const u16* Bg = Bt + (size_t)(n0 + lrow) * 512 + seg * 8;
    u16* Asl = As + lrow * 32 + seg * 8;
    u16* Bsl = Bs + lrow * 32 + seg * 8;

    const int w = tid >> 6, lane = tid & 63;
    const int wrow = (w >> 1) * 64, wcol = (w & 1) * 64;
    const int lm = lane & 15, quad = lane >> 4;

    f32x4 acc[4][4] = {};

    for (int kt = 0; kt < 16; ++kt) {
        __syncthreads();                  // prior LDS reads done before DMA overwrite
        gload_lds16(Ag + kt * 32,             Asl);
        gload_lds16(Ag + 64 * 512 + kt * 32,  Asl + 64 * 32);
        gload_lds16(Bg + kt * 32,             Bsl);
        gload_lds16(Bg + 64 * 512 + kt * 32,  Bsl + 64 * 32);
        __syncthreads();                  // drains vmcnt: DMA complete
        short8 af[4], bf[4];
        #pragma unroll
        for (int mi = 0; mi < 4; ++mi)
            af[mi] = *(const short8*)(As + (wrow + mi * 16 + lm) * 32 + quad * 8);
        #pragma unroll
        for (int ni = 0; ni < 4; ++ni)
            bf[ni] = *(const short8*)(Bs + (wcol + ni * 16 + lm) * 32 + quad * 8);
        #pragma unroll
        for (int mi = 0; mi < 4; ++mi)
            #pragma unroll
            for (int ni = 0; ni < 4; ++ni)
                acc[mi][ni] = __builtin_amdgcn_mfma_f32_16x16x32_bf16(af[mi], bf[ni], acc[mi][ni], 0, 0, 0);
    }

    if (EPI == 1) {
        #pragma unroll
        for (int ni = 0; ni < 4; ++ni) {
            int ncol = n0 + wcol + ni * 16 + lm;
            float bias = bo[ncol];
            #pragma unroll
            for (int mi = 0; mi < 4; ++mi) {
                int mbase = m0 + wrow + mi * 16 + quad * 4;
                #pragma unroll
                for (int r = 0; r < 4; ++r)
                    outf[(size_t)(mbase + r) * 512 + ncol] = acc[mi][ni][r] + bias;
            }
        }
    } else {
        #pragma unroll
        for (int ni = 0; ni < 4; ++ni) {
            int ncol = n0 + wcol + ni * 16 + lm;
            int proj = ncol >> 9, hd = ncol & 511;
            int h = hd >> 6, d = hd & 63;
            const float* bptr = (proj == 0) ? bq : (proj == 1) ? bk : bv;
            u16* dst = (proj == 0) ? Qb : (proj == 1) ? Kb : Vb;
            float bias = bptr[hd];
            #pragma unroll
            for (int mi = 0; mi < 4; ++mi) {
                int mbase = m0 + wrow + mi * 16 + quad * 4;
                #pragma unroll
                for (int r = 0; r < 4; ++r) {
                    int mrow = mbase + r;
                    int b = mrow >> 8, t = mrow & 255;
                    size_t idx = (proj == 2)
                        ? ((size_t)((b * 8 + h) * 64 + d) * 256 + t)     // Vt [head][d][t]
                        : ((size_t)((b * 8 + h) * 256 + t) * 64 + d);   // Q/K [head][t][d]
                    dst[idx] = f2bf(acc[mi][ni][r] + bias);
                }
            }
        }
    }
}

// ---------------- MFMA flash attention ----------------
// TWO wgs per (b,h): iset=0 owns i in {0,3}, iset=1 owns i in {1,2} (balanced
// 5 j-tiles each). XCD swizzle co-locates both wgs of a head on one XCD
// (shared K/Vt in that L2). K [256][64] and Vt [64][256] staged in LDS
// (16B-chunk XOR swizzle). Wave w owns 16 Q-rows at t0 = i*64 + w*16.
// P round-trips C/D->LDS->A-layout through a per-wave 2KB buffer; bracketed
// by __syncthreads() (all waves run identical trip counts).
__global__ __launch_bounds__(256)
void attn_mfma_kernel(const u16* __restrict__ Qg, const u16* __restrict__ Kg,
                      const u16* __restrict__ Vtg, u16* __restrict__ attn) {
    __shared__ __align__(16) u16 lds[36864];   // K:0..16383 | Vt:16384..32767 | P: 32768 + w*1024
    const int bid = blockIdx.x;
    const int head = (bid & 7) * 64 + ((bid >> 3) >> 1);
    const int iset = (bid >> 3) & 1;
    const int b = head >> 3, h = head & 7;
    const int tid = threadIdx.x;
    const size_t hb = (size_t)head * 16384;

    {
        const uint4* Ksrc = (const uint4*)(Kg + hb);
        const uint4* Vsrc = (const uint4*)(Vtg + hb);
        uint4* L4 = (uint4*)lds;
        #pragma unroll
        for (int it = 0; it < 8; ++it) {
            int g = it * 256 + tid;
            int kr = g >> 3, kc = g & 7;
            L4[kr * 8 + (kc ^ (kr & 7))] = Ksrc[g];
            int vr = g >> 5, vc = g & 31;
            L4[2048 + vr * 32 + (vc ^ (vr & 7))] = Vsrc[g];
        }
    }
    __syncthreads();

    const int w = tid >> 6, lane = tid & 63;
    const int lm = lane & 15, quad = lane >> 4;
    const int l7 = lm & 7;

    const int kx0 = (quad ^ l7) * 8;          // k-chunk f=0
    const int kx1 = ((4 + quad) ^ l7) * 8;    // k-chunk f=1
    const u16* Kbase = lds + lm * 64;                 // + j*4096 + ni*1024 + kx
    const u16* Vbase = lds + 16384 + lm * 256;        // + nd*4096 + j*64 + kx
    const int Pbase = 32768 + w * 1024;
    const int x0 = (lm >> 3) & 1;
    const int pw_even = Pbase + quad * 16 + l7 + x0 * 8;         // rr even
    const int pw_odd  = Pbase + quad * 16 + l7 + (x0 ^ 1) * 8;   // rr odd
    const int pr0 = Pbase + ((lm & 3) * 4 + (quad >> 1)) * 64
                  + (2 * (lm >> 2) + ((quad & 1) ^ (lm & 1))) * 8;

    #pragma unroll 1
    for (int ii = 0; ii < 2; ++ii) {
        const int i = iset ? (ii ? 2 : 1) : (ii ? 3 : 0);
        const int t0 = i * 64 + w * 16;
        short8 qa0 = *(const short8*)(Qg + hb + (size_t)(t0 + lm) * 64 + quad * 8);
        short8 qa1 = *(const short8*)(Qg + hb + (size_t)(t0 + lm) * 64 + 32 + quad * 8);
        f32x4 O[4] = {};
        float mr[4] = {-INFINITY, -INFINITY, -INFINITY, -INFINITY};
        float lr[4] = {0.f, 0.f, 0.f, 0.f};

        #pragma unroll 1
        for (int j = 0; j <= i; ++j) {
            f32x4 S[4] = {};
            #pragma unroll
            for (int ni = 0; ni < 4; ++ni) {
                const u16* kp = Kbase + j * 4096 + ni * 1024;
                short8 kb0 = *(const short8*)(kp + kx0);
                short8 kb1 = *(const short8*)(kp + kx1);
                S[ni] = __builtin_amdgcn_mfma_f32_16x16x32_bf16(qa0, kb0, S[ni], 0, 0, 0);
                S[ni] = __builtin_amdgcn_mfma_f32_16x16x32_bf16(qa1, kb1, S[ni], 0, 0, 0);
            }
            if (j == i) {
                #pragma unroll
                for (int ni = 0; ni < 4; ++ni) {
                    int scol = ni * 16 + lm;
                    #pragma unroll
                    for (int rr = 0; rr < 4; ++rr) {
                        int tloc = w * 16 + quad * 4 + rr;
                        S[ni][rr] = (scol > tloc) ? -INFINITY : S[ni][rr] * 0.125f;
                    }
                }
            } else {
                #pragma unroll
                for (int ni = 0; ni < 4; ++ni)
                    #pragma unroll
                    for (int rr = 0; rr < 4; ++rr)
                        S[ni][rr] *= 0.125f;
            }
            float alpha[4];
            #pragma unroll
            for (int rr = 0; rr < 4; ++rr) {
                float mx = fmaxf(fmaxf(S[0][rr], S[1][rr]), fmaxf(S[2][rr], S[3][rr]));
                mx = fmaxf(mx, __shfl_xor(mx, 1));
                mx = fmaxf(mx, __shfl_xor(mx, 2));
                mx = fmaxf(mx, __shfl_xor(mx, 4));
                mx = fmaxf(mx, __shfl_xor(mx, 8));
                float mnew = fmaxf(mr[rr], mx);
                alpha[rr] = __expf(mr[rr] - mnew);   // 0 on first tile (-inf - finite)
                mr[rr] = mnew;
            }
            __syncthreads();   // previous iter's P reads complete before overwrite
            float rs[4] = {0.f, 0.f, 0.f, 0.f};
            #pragma unroll
            for (int ni = 0; ni < 4; ++ni) {
                #pragma unroll
                for (int rr = 0; rr < 4; ++rr) {
                    float p = __expf(S[ni][rr] - mr[rr]);   // 0 for masked (-inf)
                    rs[rr] += p;
                    int addr = ((rr & 1) ? pw_odd : pw_even) + (rr * 4 + ni) * 64;
                    lds[addr] = f2bf(p);
                }
            }
            #pragma unroll
            for (int rr = 0; rr < 4; ++rr) {
                float s = rs[rr];
                s += __shfl_xor(s, 1);
                s += __shfl_xor(s, 2);
                s += __shfl_xor(s, 4);
                s += __shfl_xor(s, 8);
                lr[rr] = lr[rr] * alpha[rr] + s;
                O[0][rr] *= alpha[rr]; O[1][rr] *= alpha[rr];
                O[2][rr] *= alpha[rr]; O[3][rr] *= alpha[rr];
            }
            __syncthreads();   // P writes visible before A-layout reads
            short8 pa0 = *(const short8*)(lds + pr0);
            short8 pa1 = *(const short8*)(lds + pr0 + 128);
            #pragma unroll
            for (int nd = 0; nd < 4; ++nd) {
                const u16* vp = Vbase + nd * 4096 + j * 64;
                short8 vb0 = *(const short8*)(vp + kx0);
                short8 vb1 = *(const short8*)(vp + kx1);
                O[nd] = __builtin_amdgcn_mfma_f32_16x16x32_bf16(pa0, vb0, O[nd], 0, 0, 0);
                O[nd] = __builtin_amdgcn_mfma_f32_16x16x32_bf16(pa1, vb1, O[nd], 0, 0, 0);
            }
        }
        #pragma unroll
        for (int rr = 0; rr < 4; ++rr) {
            float inv = 1.0f / lr[rr];
            int t = t0 + quad * 4 + rr;
            u16* op = attn + (size_t)(b * 256 + t) * 512 + h * 64 + lm;
            op[0]  = f2bf(O[0][rr] * inv);
            op[16] = f2bf(O[1][rr] * inv);
            op[32] = f2bf(O[2][rr] * inv);
            op[48] = f2bf(O[3][rr] * inv);
        }
    }
}

extern "C" void kernel_launch(void* const* d_in, const int* in_sizes, int n_in,
                              void* d_out, int out_size, void* d_ws, size_t ws_size,
                              hipStream_t stream) {
    const float* x  = (const float*)d_in[0];
    const float* wq = (const float*)d_in[1];
    const float* wk = (const float*)d_in[2];
    const float* wv = (const float*)d_in[3];
    const float* bq = (const float*)d_in[4];
    const float* bk = (const float*)d_in[5];
    const float* bv = (const float*)d_in[6];
    const float* wo = (const float*)d_in[7];
    const float* bo = (const float*)d_in[8];
    float* out = (float*)d_out;

    char* ws = (char*)d_ws;
    const size_t SZ = 16777216;                  // 16384*512*2 bytes
    u16* xb    = (u16*)(ws);
    u16* Qb    = (u16*)(ws + SZ);
    u16* Kb    = (u16*)(ws + 2 * SZ);
    u16* Vt    = (u16*)(ws + 3 * SZ);            // [head][d][t] (written by gemm<0>)
    u16* attn  = (u16*)(ws + 4 * SZ);
    u16* wqkvT = (u16*)(ws + 5 * SZ);
    u16* woT   = (u16*)(ws + 5 * SZ + 1572864);

    cast_x_kernel<<<8192, 256, 0, stream>>>(x, xb);
    pack_wqkv_kernel<<<3072, 256, 0, stream>>>(wq, wk, wv, wqkvT);
    pack_wo_kernel<<<1024, 256, 0, stream>>>(wo, woT);

    gemm128_kernel<0, 12><<<1536, 256, 0, stream>>>(
        xb, wqkvT, nullptr, nullptr, Qb, Kb, Vt, bq, bk, bv);

    attn_mfma_kernel<<<1024, 256, 0, stream>>>(Qb, Kb, Vt, attn);

    gemm128_kernel<1, 4><<<512, 256, 0, stream>>>(
        attn, woT, out, bo, nullptr, nullptr, nullptr, nullptr, nullptr, nullptr);
}

// Round 6
// 211.314 us; speedup vs baseline: 1.0368x; 1.0063x over previous
//
#include <hip/hip_runtime.h>

typedef unsigned int   u32;
typedef unsigned short u16;
typedef __attribute__((ext_vector_type(8))) short short8;
typedef __attribute__((ext_vector_type(4))) float f32x4;

// B=64 T=256 C=512 H=8 D=64; M = B*T = 16384; K = 512; Nqkv = 1536

__device__ __forceinline__ u16 f2bf(float f) {
    u32 u = __float_as_uint(f);
    u += 0x7fffu + ((u >> 16) & 1u);   // RNE
    return (u16)(u >> 16);
}

// async global->LDS 16B (direct DMA, no VGPR round-trip). LDS dest is
// wave-uniform base + lane*16.
__device__ __forceinline__ void gload_lds16(const u16* g, u16* l) {
    __builtin_amdgcn_global_load_lds(
        (const __attribute__((address_space(1))) u32*)(const void*)g,
        (__attribute__((address_space(3))) u32*)(void*)l, 16, 0, 0);
}

// ---------------- cast x (fp32 -> bf16) ----------------
__global__ void cast_x_kernel(const float* __restrict__ x, u16* __restrict__ xb) {
    int i = blockIdx.x * 256 + threadIdx.x;
    float4 v = ((const float4*)x)[i];
    ushort4 o;
    o.x = f2bf(v.x); o.y = f2bf(v.y); o.z = f2bf(v.z); o.w = f2bf(v.w);
    ((ushort4*)xb)[i] = o;
}

// -------- pack wq|wk|wv -> bf16 [1536][512] transposed --------
__global__ void pack_wqkv_kernel(const float* __restrict__ wq, const float* __restrict__ wk,
                                 const float* __restrict__ wv, u16* __restrict__ wt) {
    int i = blockIdx.x * 256 + threadIdx.x;
    int n = i >> 9, c = i & 511;
    int proj = n >> 9, hd = n & 511;
    int h = hd >> 6, d = hd & 63;
    const float* w = (proj == 0) ? wq : (proj == 1) ? wk : wv;
    wt[(size_t)n * 512 + c] = f2bf(w[h * 32768 + c * 64 + d]);
}

// -------- pack wo [512][512] -> bf16 transposed [n][k] --------
__global__ void pack_wo_kernel(const float* __restrict__ wo, u16* __restrict__ wt) {
    int i = blockIdx.x * 256 + threadIdx.x;
    int n = i >> 9, k = i & 511;
    wt[(size_t)n * 512 + k] = f2bf(wo[(size_t)k * 512 + n]);
}

// ---------------- 128x128 bf16 MFMA GEMM, K=512, TN, global_load_lds staging ----
// LDS tile rows are 64B (4 x 16B chunks). Chunk c of row r lives at slot
// c ^ ((r>>1)&3): staging lane (lrow,seg) fetches global chunk seg^((lrow>>1)&3)
// (DMA dest stays lane-contiguous); fragment b128 reads use chunk
// quad^((lm>>1)&3). Every in-order group of 8 lanes then covers all 8
// bank-groups -> conflict-free (was 4x-conflicted: slot mod 8 hit only
// 2 groups). XCD swizzle: block i -> XCD i%8; XCD x owns m-stripes
// [x*16,(x+1)*16) for all NT n-tiles (A fetched once per XCD, B L2-resident).
template<int EPI, int NT>
__global__ __launch_bounds__(256)
void gemm128_kernel(const u16* __restrict__ A, const u16* __restrict__ Bt,
                    float* __restrict__ outf, const float* __restrict__ bo,
                    u16* __restrict__ Qb, u16* __restrict__ Kb, u16* __restrict__ Vb,
                    const float* __restrict__ bq, const float* __restrict__ bk,
                    const float* __restrict__ bv) {
    __shared__ __align__(16) u16 As[128 * 32];
    __shared__ __align__(16) u16 Bs[128 * 32];
    const int tid = threadIdx.x;
    const int bid = blockIdx.x;
    const int xcd = bid & 7;
    const int k8  = bid >> 3;                 // 0 .. 16*NT-1
    const int m0 = (xcd * 16 + k8 / NT) * 128;
    const int n0 = (k8 % NT) * 128;
    const int lrow = tid >> 2;            // 0..63
    const int seg  = tid & 3;
    const int xsw  = (lrow >> 1) & 3;     // chunk-xor (same for row lrow+64)
    const u16* Ag = A  + (size_t)(m0 + lrow) * 512 + (seg ^ xsw) * 8;
    const u16* Bg = Bt + (size_t)(n0 + lrow) * 512 + (seg ^ xsw) * 8;
    u16* Asl = As + lrow * 32 + seg * 8;
    u16* Bsl = Bs + lrow * 32 + seg * 8;

    const int w = tid >> 6, lane = tid & 63;
    const int wrow = (w >> 1) * 64, wcol = (w & 1) * 64;
    const int lm = lane & 15, quad = lane >> 4;
    const int kx = (quad ^ ((lm >> 1) & 3)) * 8;   // frag chunk position

    f32x4 acc[4][4] = {};

    for (int kt = 0; kt < 16; ++kt) {
        __syncthreads();                  // prior LDS reads done before DMA overwrite
        gload_lds16(Ag + kt * 32,             Asl);
        gload_lds16(Ag + 64 * 512 + kt * 32,  Asl + 64 * 32);
        gload_lds16(Bg + kt * 32,             Bsl);
        gload_lds16(Bg + 64 * 512 + kt * 32,  Bsl + 64 * 32);
        __syncthreads();                  // drains vmcnt: DMA complete
        short8 af[4], bf[4];
        #pragma unroll
        for (int mi = 0; mi < 4; ++mi)
            af[mi] = *(const short8*)(As + (wrow + mi * 16 + lm) * 32 + kx);
        #pragma unroll
        for (int ni = 0; ni < 4; ++ni)
            bf[ni] = *(const short8*)(Bs + (wcol + ni * 16 + lm) * 32 + kx);
        #pragma unroll
        for (int mi = 0; mi < 4; ++mi)
            #pragma unroll
            for (int ni = 0; ni < 4; ++ni)
                acc[mi][ni] = __builtin_amdgcn_mfma_f32_16x16x32_bf16(af[mi], bf[ni], acc[mi][ni], 0, 0, 0);
    }

    if (EPI == 1) {
        #pragma unroll
        for (int ni = 0; ni < 4; ++ni) {
            int ncol = n0 + wcol + ni * 16 + lm;
            float bias = bo[ncol];
            #pragma unroll
            for (int mi = 0; mi < 4; ++mi) {
                int mbase = m0 + wrow + mi * 16 + quad * 4;
                #pragma unroll
                for (int r = 0; r < 4; ++r)
                    outf[(size_t)(mbase + r) * 512 + ncol] = acc[mi][ni][r] + bias;
            }
        }
    } else {
        #pragma unroll
        for (int ni = 0; ni < 4; ++ni) {
            int ncol = n0 + wcol + ni * 16 + lm;
            int proj = ncol >> 9, hd = ncol & 511;
            int h = hd >> 6, d = hd & 63;
            const float* bptr = (proj == 0) ? bq : (proj == 1) ? bk : bv;
            u16* dst = (proj == 0) ? Qb : (proj == 1) ? Kb : Vb;
            float bias = bptr[hd];
            #pragma unroll
            for (int mi = 0; mi < 4; ++mi) {
                int mbase = m0 + wrow + mi * 16 + quad * 4;
                #pragma unroll
                for (int r = 0; r < 4; ++r) {
                    int mrow = mbase + r;
                    int b = mrow >> 8, t = mrow & 255;
                    size_t idx = (proj == 2)
                        ? ((size_t)((b * 8 + h) * 64 + d) * 256 + t)     // Vt [head][d][t]
                        : ((size_t)((b * 8 + h) * 256 + t) * 64 + d);   // Q/K [head][t][d]
                    dst[idx] = f2bf(acc[mi][ni][r] + bias);
                }
            }
        }
    }
}

// ---------------- MFMA flash attention ----------------
// TWO wgs per (b,h) (iset 0: i in {0,3}; iset 1: i in {1,2} — 5 j-tiles each),
// XCD-co-located. Only K [256][64] staged in LDS (XOR 16B-chunk swizzle,
// conflict-free); V fragments are read DIRECTLY from global Vt[head][d][t]
// (natural row-major b128, L2-resident 32KB/head). LDS = 32KB K + 8KB P
// -> 40KB/wg. P is wave-private; one __syncthreads per j-tile between P-write
// and P-read (ordering paranoia; all waves run identical trip counts).
__global__ __launch_bounds__(256)
void attn_mfma_kernel(const u16* __restrict__ Qg, const u16* __restrict__ Kg,
                      const u16* __restrict__ Vtg, u16* __restrict__ attn) {
    __shared__ __align__(16) u16 lds[20480];   // K:0..16383 | P: 16384 + w*1024
    const int bid = blockIdx.x;
    const int head = (bid & 7) * 64 + ((bid >> 3) >> 1);
    const int iset = (bid >> 3) & 1;
    const int b = head >> 3, h = head & 7;
    const int tid = threadIdx.x;
    const size_t hb = (size_t)head * 16384;

    {
        const uint4* Ksrc = (const uint4*)(Kg + hb);
        uint4* L4 = (uint4*)lds;
        #pragma unroll
        for (int it = 0; it < 8; ++it) {
            int g = it * 256 + tid;
            int kr = g >> 3, kc = g & 7;
            L4[kr * 8 + (kc ^ (kr & 7))] = Ksrc[g];
        }
    }
    __syncthreads();

    const int w = tid >> 6, lane = tid & 63;
    const int lm = lane & 15, quad = lane >> 4;
    const int l7 = lm & 7;

    const int kx0 = (quad ^ l7) * 8;          // K k-chunk f=0 (8 chunks/128B row)
    const int kx1 = ((4 + quad) ^ l7) * 8;    // K k-chunk f=1
    const u16* Kbase = lds + lm * 64;                 // + j*4096 + ni*1024 + kx
    const u16* Vg = Vtg + hb;                         // [d][t], global
    const int Pbase = 16384 + w * 1024;
    const int x0 = (lm >> 3) & 1;
    const int pw_even = Pbase + quad * 16 + l7 + x0 * 8;         // rr even
    const int pw_odd  = Pbase + quad * 16 + l7 + (x0 ^ 1) * 8;   // rr odd
    const int pr0 = Pbase + ((lm & 3) * 4 + (quad >> 1)) * 64
                  + (2 * (lm >> 2) + ((quad & 1) ^ (lm & 1))) * 8;

    #pragma unroll 1
    for (int ii = 0; ii < 2; ++ii) {
        const int i = iset ? (ii ? 2 : 1) : (ii ? 3 : 0);
        const int t0 = i * 64 + w * 16;
        short8 qa0 = *(const short8*)(Qg + hb + (size_t)(t0 + lm) * 64 + quad * 8);
        short8 qa1 = *(const short8*)(Qg + hb + (size_t)(t0 + lm) * 64 + 32 + quad * 8);
        f32x4 O[4] = {};
        float mr[4] = {-INFINITY, -INFINITY, -INFINITY, -INFINITY};
        float lr[4] = {0.f, 0.f, 0.f, 0.f};

        #pragma unroll 1
        for (int j = 0; j <= i; ++j) {
            f32x4 S[4] = {};
            #pragma unroll
            for (int ni = 0; ni < 4; ++ni) {
                const u16* kp = Kbase + j * 4096 + ni * 1024;
                short8 kb0 = *(const short8*)(kp + kx0);
                short8 kb1 = *(const short8*)(kp + kx1);
                S[ni] = __builtin_amdgcn_mfma_f32_16x16x32_bf16(qa0, kb0, S[ni], 0, 0, 0);
                S[ni] = __builtin_amdgcn_mfma_f32_16x16x32_bf16(qa1, kb1, S[ni], 0, 0, 0);
            }
            if (j == i) {
                #pragma unroll
                for (int ni = 0; ni < 4; ++ni) {
                    int scol = ni * 16 + lm;
                    #pragma unroll
                    for (int rr = 0; rr < 4; ++rr) {
                        int tloc = w * 16 + quad * 4 + rr;
                        S[ni][rr] = (scol > tloc) ? -INFINITY : S[ni][rr] * 0.125f;
                    }
                }
            } else {
                #pragma unroll
                for (int ni = 0; ni < 4; ++ni)
                    #pragma unroll
                    for (int rr = 0; rr < 4; ++rr)
                        S[ni][rr] *= 0.125f;
            }
            float alpha[4];
            #pragma unroll
            for (int rr = 0; rr < 4; ++rr) {
                float mx = fmaxf(fmaxf(S[0][rr], S[1][rr]), fmaxf(S[2][rr], S[3][rr]));
                mx = fmaxf(mx, __shfl_xor(mx, 1));
                mx = fmaxf(mx, __shfl_xor(mx, 2));
                mx = fmaxf(mx, __shfl_xor(mx, 4));
                mx = fmaxf(mx, __shfl_xor(mx, 8));
                float mnew = fmaxf(mr[rr], mx);
                alpha[rr] = __expf(mr[rr] - mnew);   // 0 on first tile (-inf - finite)
                mr[rr] = mnew;
            }
            float rs[4] = {0.f, 0.f, 0.f, 0.f};
            #pragma unroll
            for (int ni = 0; ni < 4; ++ni) {
                #pragma unroll
                for (int rr = 0; rr < 4; ++rr) {
                    float p = __expf(S[ni][rr] - mr[rr]);   // 0 for masked (-inf)
                    rs[rr] += p;
                    int addr = ((rr & 1) ? pw_odd : pw_even) + (rr * 4 + ni) * 64;
                    lds[addr] = f2bf(p);
                }
            }
            #pragma unroll
            for (int rr = 0; rr < 4; ++rr) {
                float s = rs[rr];
                s += __shfl_xor(s, 1);
                s += __shfl_xor(s, 2);
                s += __shfl_xor(s, 4);
                s += __shfl_xor(s, 8);
                lr[rr] = lr[rr] * alpha[rr] + s;
                O[0][rr] *= alpha[rr]; O[1][rr] *= alpha[rr];
                O[2][rr] *= alpha[rr]; O[3][rr] *= alpha[rr];
            }
            __syncthreads();   // P write -> read ordering (wave-private; paranoia)
            short8 pa0 = *(const short8*)(lds + pr0);
            short8 pa1 = *(const short8*)(lds + pr0 + 128);
            #pragma unroll
            for (int nd = 0; nd < 4; ++nd) {
                const u16* vp = Vg + (size_t)(nd * 16 + lm) * 256 + j * 64;
                short8 vb0 = *(const short8*)(vp + quad * 8);        // s = j*64+quad*8..+7
                short8 vb1 = *(const short8*)(vp + 32 + quad * 8);   // s = +32
                O[nd] = __builtin_amdgcn_mfma_f32_16x16x32_bf16(pa0, vb0, O[nd], 0, 0, 0);
                O[nd] = __builtin_amdgcn_mfma_f32_16x16x32_bf16(pa1, vb1, O[nd], 0, 0, 0);
            }
        }
        #pragma unroll
        for (int rr = 0; rr < 4; ++rr) {
            float inv = 1.0f / lr[rr];
            int t = t0 + quad * 4 + rr;
            u16* op = attn + (size_t)(b * 256 + t) * 512 + h * 64 + lm;
            op[0]  = f2bf(O[0][rr] * inv);
            op[16] = f2bf(O[1][rr] * inv);
            op[32] = f2bf(O[2][rr] * inv);
            op[48] = f2bf(O[3][rr] * inv);
        }
    }
}

extern "C" void kernel_launch(void* const* d_in, const int* in_sizes, int n_in,
                              void* d_out, int out_size, void* d_ws, size_t ws_size,
                              hipStream_t stream) {
    const float* x  = (const float*)d_in[0];
    const float* wq = (const float*)d_in[1];
    const float* wk = (const float*)d_in[2];
    const float* wv = (const float*)d_in[3];
    const float* bq = (const float*)d_in[4];
    const float* bk = (const float*)d_in[5];
    const float* bv = (const float*)d_in[6];
    const float* wo = (const float*)d_in[7];
    const float* bo = (const float*)d_in[8];
    float* out = (float*)d_out;

    char* ws = (char*)d_ws;
    const size_t SZ = 16777216;                  // 16384*512*2 bytes
    u16* xb    = (u16*)(ws);
    u16* Qb    = (u16*)(ws + SZ);
    u16* Kb    = (u16*)(ws + 2 * SZ);
    u16* Vt    = (u16*)(ws + 3 * SZ);            // [head][d][t] (written by gemm<0>)
    u16* attn  = (u16*)(ws + 4 * SZ);
    u16* wqkvT = (u16*)(ws + 5 * SZ);
    u16* woT   = (u16*)(ws + 5 * SZ + 1572864);

    cast_x_kernel<<<8192, 256, 0, stream>>>(x, xb);
    pack_wqkv_kernel<<<3072, 256, 0, stream>>>(wq, wk, wv, wqkvT);
    pack_wo_kernel<<<1024, 256, 0, stream>>>(wo, woT);

    gemm128_kernel<0, 12><<<1536, 256, 0, stream>>>(
        xb, wqkvT, nullptr, nullptr, Qb, Kb, Vt, bq, bk, bv);

    attn_mfma_kernel<<<1024, 256, 0, stream>>>(Qb, Kb, Vt, attn);

    gemm128_kernel<1, 4><<<512, 256, 0, stream>>>(
        attn, woT, out, bo, nullptr, nullptr, nullptr, nullptr, nullptr, nullptr);
}